// Round 2
// baseline (935.167 us; speedup 1.0000x reference)
//
#include <hip/hip_runtime.h>

typedef unsigned short ushort_t;
typedef unsigned int uint_t;

#define BKT_SHIFT 6            // 64 dst-nodes per bucket
#define BKT_NODES 64
#define BCAP 2048              // slots per bucket; mean 1600, +11 sigma (uniform-random edges)
#define EPB 8192               // edges per scatter block (512 thr x 16)

__device__ __forceinline__ ushort_t f2bf(float f) {
    unsigned u = __float_as_uint(f);
    unsigned r = (u + 0x7FFFu + ((u >> 16) & 1u)) >> 16;   // RNE
    return (ushort_t)r;
}
__device__ __forceinline__ float bflo(uint_t u) { return __uint_as_float(u << 16); }
__device__ __forceinline__ float bfhi(uint_t u) { return __uint_as_float(u & 0xFFFF0000u); }

// ---- fat kernel: atomic-claim bucket scatter  ||  z1 = x @ W1 (bf16) ----
// blocks [0, SBLK): one pass over edges, claim a slot in dst's bucket via
//   global atomic (1563 counters, ~1600 claims each -> channel-parallel).
// blocks [SBLK, ...): per-node 32->16 matvec, bf16 out (GIN distributivity:
//   (x_i + sum x_j)@W1 = z_i + sum z_j, so aggregation runs in 16-ch space).
__global__ __launch_bounds__(512) void scatter_lin(
    const int* __restrict__ src, const int* __restrict__ dst,
    int* __restrict__ gcur, int* __restrict__ staged,
    const float4* __restrict__ x4, const float* __restrict__ W,
    ushort_t* __restrict__ z, int E, int SBLK, int N)
{
    __shared__ float sW[512];
    int t = threadIdx.x, blk = blockIdx.x;
    if (blk < SBLK) {
        int e0 = blk * EPB;
        #pragma unroll
        for (int i = 0; i < 16; ++i) {
            int e = e0 + i * 512 + t;
            if (e < E) {
                int d = dst[e], s = src[e];
                int b = d >> BKT_SHIFT;
                int r = atomicAdd(&gcur[b], 1);
                if (r < BCAP)   // statistically unreachable overflow guard
                    staged[(size_t)b * BCAP + r] = ((d & (BKT_NODES - 1)) << 24) | s;
            }
        }
    } else {
        sW[t] = W[t];                      // 32x16 = 512 floats
        __syncthreads();
        int n = (blk - SBLK) * 512 + t;
        if (n >= N) return;
        float a[16];
        #pragma unroll
        for (int c = 0; c < 16; ++c) a[c] = 0.f;
        const float4* xr = x4 + (size_t)n * 8;
        #pragma unroll
        for (int k4 = 0; k4 < 8; ++k4) {
            float4 xv = xr[k4];
            #pragma unroll
            for (int c = 0; c < 16; ++c) {
                a[c] += xv.x * sW[(k4 * 4 + 0) * 16 + c];
                a[c] += xv.y * sW[(k4 * 4 + 1) * 16 + c];
                a[c] += xv.z * sW[(k4 * 4 + 2) * 16 + c];
                a[c] += xv.w * sW[(k4 * 4 + 3) * 16 + c];
            }
        }
        uint_t w[8];
        #pragma unroll
        for (int i2 = 0; i2 < 8; ++i2)
            w[i2] = (uint_t)f2bf(a[2 * i2]) | ((uint_t)f2bf(a[2 * i2 + 1]) << 16);
        uint4* zo = (uint4*)(z + (size_t)n * 16);
        uint4 q0; q0.x = w[0]; q0.y = w[1]; q0.z = w[2]; q0.w = w[3];
        uint4 q1; q1.x = w[4]; q1.y = w[5]; q1.z = w[6]; q1.w = w[7];
        zo[0] = q0;     // cacheable: consumed by agg gathers next
        zo[1] = q1;
    }
}

// ---- Fused bucket aggregate + MLP --------------------------------------
// One block per 64-node bucket (1563 blocks ~ 6/CU, single residency wave).
// 4 lanes per edge (uint2 = 4ch each); neighbor rows accumulated straight
// into a padded fp32 LDS accumulator via ds_add_f32 (stride 17 spreads
// banks; z table = 3.2 MB -> L2-resident, no ordering needed).
// Epilogue: h = ReLU(z_i + acc + ba);  o = h@Wb + bb
//   CHAIN:  z_next = ReLU(o)@Wc -> bf16   (feeds conv2's aggregation)
//   !CHAIN: o -> fp32 final output

template <bool CHAIN>
__global__ __launch_bounds__(256) void agg_fused(
    const ushort_t* __restrict__ zin, const int* __restrict__ staged,
    const int* __restrict__ gcur,
    const float* __restrict__ ba,
    const float* __restrict__ Wb, const float* __restrict__ bb,
    const float* __restrict__ Wc,
    void* __restrict__ outv, int N)
{
    __shared__ float acc[BKT_NODES * 17];
    __shared__ float sWb[512];
    __shared__ float sWc[512];
    __shared__ float sba[16], sbb[32];
    __shared__ float sh[BKT_NODES * 17];
    __shared__ float sr[BKT_NODES * 33];

    int t = threadIdx.x;
    sWb[t] = Wb[t];  sWb[t + 256] = Wb[t + 256];
    if (CHAIN) { sWc[t] = Wc[t];  sWc[t + 256] = Wc[t + 256]; }
    if (t < 16) sba[t] = ba[t];
    if (t < 32) sbb[t] = bb[t];
    #pragma unroll
    for (int i = t; i < BKT_NODES * 17; i += 256) acc[i] = 0.f;
    __syncthreads();

    int b = blockIdx.x;
    int m = min(gcur[b], BCAP);
    const int* sp = staged + (size_t)b * BCAP;
    int sl = t & 3;           // channel quarter 4*sl .. 4*sl+3
    int eo = t >> 2;          // edge slot 0..63
    int cb = sl * 4;
    const uint2* zp = (const uint2*)zin;   // z row = 4 uint2 (16 bf16)

    int i = eo;
    for (; i + 64 < m; i += 128) {         // 2 independent chains in flight
        int v0 = sp[i];
        int v1 = sp[i + 64];
        int dl0 = ((unsigned)v0) >> 24, s0 = v0 & 0xFFFFFF;
        int dl1 = ((unsigned)v1) >> 24, s1 = v1 & 0xFFFFFF;
        uint2 u0 = zp[(size_t)s0 * 4 + sl];
        uint2 u1 = zp[(size_t)s1 * 4 + sl];
        atomicAdd(&acc[dl0 * 17 + cb + 0], bflo(u0.x));
        atomicAdd(&acc[dl0 * 17 + cb + 1], bfhi(u0.x));
        atomicAdd(&acc[dl0 * 17 + cb + 2], bflo(u0.y));
        atomicAdd(&acc[dl0 * 17 + cb + 3], bfhi(u0.y));
        atomicAdd(&acc[dl1 * 17 + cb + 0], bflo(u1.x));
        atomicAdd(&acc[dl1 * 17 + cb + 1], bfhi(u1.x));
        atomicAdd(&acc[dl1 * 17 + cb + 2], bflo(u1.y));
        atomicAdd(&acc[dl1 * 17 + cb + 3], bfhi(u1.y));
    }
    if (i < m) {
        int v = sp[i];
        int dl = ((unsigned)v) >> 24, s = v & 0xFFFFFF;
        uint2 u = zp[(size_t)s * 4 + sl];
        atomicAdd(&acc[dl * 17 + cb + 0], bflo(u.x));
        atomicAdd(&acc[dl * 17 + cb + 1], bfhi(u.x));
        atomicAdd(&acc[dl * 17 + cb + 2], bflo(u.y));
        atomicAdd(&acc[dl * 17 + cb + 3], bfhi(u.y));
    }
    __syncthreads();

    int ln = t >> 2;                        // node slot 0..63
    int n = (b << BKT_SHIFT) + ln;
    bool act = (n < N);
    if (act) {
        uint2 us = zp[(size_t)n * 4 + sl];  // self term
        float v0 = acc[ln * 17 + cb + 0] + bflo(us.x);
        float v1 = acc[ln * 17 + cb + 1] + bfhi(us.x);
        float v2 = acc[ln * 17 + cb + 2] + bflo(us.y);
        float v3 = acc[ln * 17 + cb + 3] + bfhi(us.y);
        sh[ln * 17 + cb + 0] = fmaxf(v0 + sba[cb + 0], 0.f);
        sh[ln * 17 + cb + 1] = fmaxf(v1 + sba[cb + 1], 0.f);
        sh[ln * 17 + cb + 2] = fmaxf(v2 + sba[cb + 2], 0.f);
        sh[ln * 17 + cb + 3] = fmaxf(v3 + sba[cb + 3], 0.f);
    }
    __syncthreads();

    if (act) {   // out channels 8*sl .. 8*sl+7 of o = h@Wb + bb
        int c0 = sl * 8;
        float o[8];
        #pragma unroll
        for (int j = 0; j < 8; ++j) o[j] = sbb[c0 + j];
        #pragma unroll
        for (int j = 0; j < 16; ++j) {
            float hj = sh[ln * 17 + j];
            #pragma unroll
            for (int cc = 0; cc < 8; ++cc)
                o[cc] += hj * sWb[j * 32 + c0 + cc];
        }
        if (CHAIN) {
            #pragma unroll
            for (int cc = 0; cc < 8; ++cc)
                sr[ln * 33 + c0 + cc] = fmaxf(o[cc], 0.f);
        } else {
            float* op = (float*)outv + (size_t)n * 32 + c0;
            #pragma unroll
            for (int cc = 0; cc < 8; ++cc)
                __builtin_nontemporal_store(o[cc], op + cc);
        }
    }
    if (CHAIN) {
        __syncthreads();
        if (act) {   // z_next channels 4*sl .. 4*sl+3 = ReLU(o) @ Wc
            int c0 = sl * 4;
            float a0 = 0.f, a1 = 0.f, a2 = 0.f, a3 = 0.f;
            #pragma unroll
            for (int j = 0; j < 32; ++j) {
                float rj = sr[ln * 33 + j];
                a0 += rj * sWc[j * 16 + c0 + 0];
                a1 += rj * sWc[j * 16 + c0 + 1];
                a2 += rj * sWc[j * 16 + c0 + 2];
                a3 += rj * sWc[j * 16 + c0 + 3];
            }
            uint_t p0 = (uint_t)f2bf(a0) | ((uint_t)f2bf(a1) << 16);
            uint_t p1 = (uint_t)f2bf(a2) | ((uint_t)f2bf(a3) << 16);
            uint_t* op = (uint_t*)outv + (size_t)n * 8 + sl * 2;
            op[0] = p0;    // cacheable: consumed by next conv's gather
            op[1] = p1;
        }
    }
}

// ---- Launch -------------------------------------------------------------

extern "C" void kernel_launch(void* const* d_in, const int* in_sizes, int n_in,
                              void* d_out, int out_size, void* d_ws, size_t ws_size,
                              hipStream_t stream) {
    const float* x  = (const float*)d_in[0];
    const int*   ei = (const int*)d_in[1];
    const float* W1 = (const float*)d_in[2];
    const float* b1 = (const float*)d_in[3];
    const float* W2 = (const float*)d_in[4];
    const float* b2 = (const float*)d_in[5];
    const float* W3 = (const float*)d_in[6];
    const float* b3 = (const float*)d_in[7];
    const float* W4 = (const float*)d_in[8];
    const float* b4 = (const float*)d_in[9];

    const int N = in_sizes[0] / 32;
    const int E = in_sizes[1] / 2;
    const int* src = ei;
    const int* dst = ei + E;

    const int NBKT = (N + BKT_NODES - 1) >> BKT_SHIFT;   // 1563
    const int SBLK = (E + EPB - 1) / EPB;                // 306
    const int LINB = (N + 511) / 512;                    // 196

    char* ws = (char*)d_ws;
    size_t o = 0;
    auto alloc = [&](size_t bytes) -> char* {
        o = (o + 255) & ~(size_t)255;
        char* r = ws + o;
        o += bytes;
        return r;
    };
    int*      gcur   = (int*)     alloc(4 * (size_t)NBKT);
    int*      staged = (int*)     alloc(4 * (size_t)NBKT * BCAP);   // 12.8 MB
    ushort_t* zb     = (ushort_t*)alloc(2 * (size_t)N * 16);        // z1 = x@W1
    ushort_t* z2b    = (ushort_t*)alloc(2 * (size_t)N * 16);        // z2 = relu(out1)@W3

    hipMemsetAsync(gcur, 0, 4 * (size_t)NBKT, stream);

    scatter_lin<<<SBLK + LINB, 512, 0, stream>>>(
        src, dst, gcur, staged, (const float4*)x, W1, zb, E, SBLK, N);

    agg_fused<true ><<<NBKT, 256, 0, stream>>>(
        zb, staged, gcur, b1, W2, b2, W3, z2b, N);
    agg_fused<false><<<NBKT, 256, 0, stream>>>(
        z2b, staged, gcur, b3, W4, b4, nullptr, d_out, N);
}

// Round 3
// 177.405 us; speedup vs baseline: 5.2714x; 5.2714x over previous
//
#include <hip/hip_runtime.h>

typedef unsigned short ushort_t;
typedef unsigned int uint_t;

#define BKT_SHIFT 8            // 256 dst-nodes per bucket
#define BKT_NODES 256
#define NBKT_MAX 400           // >= ceil(100000/256)=391
#define BCAP 8192              // slots per bucket; mean 6400, sigma~80 -> +22 sigma
#define EPB 8192               // edges per scatter block (512 thr x 16 in regs)
#define NPB16 64               // nodes per agg block
#define SCOL_N16 2560          // LDS col cache per agg block (mean 1600, +24 sigma)

__device__ __forceinline__ ushort_t f2bf(float f) {
    unsigned u = __float_as_uint(f);
    unsigned r = (u + 0x7FFFu + ((u >> 16) & 1u)) >> 16;   // RNE
    return (ushort_t)r;
}
__device__ __forceinline__ float bflo(uint_t u) { return __uint_as_float(u << 16); }
__device__ __forceinline__ float bfhi(uint_t u) { return __uint_as_float(u & 0xFFFF0000u); }

// ---- fat kernel: range-claim bucket scatter  ||  z1 = x @ W1 (bf16) ----
// Scatter blocks: 16 edges/thread held in REGISTERS; LDS histogram over 391
// buckets; ONE global atomicAdd per (block,bucket) claims a contiguous range
// (120K atomics total, ~306 per address -> parallel across addresses); place
// via LDS rank atomics. Per-edge atomics never leave LDS (round-2 lesson).
// Lin blocks: per-node 32->16 matvec, bf16 out (GIN distributivity:
// (x_i + sum x_j)@W1 = z_i + sum z_j, so aggregation runs in 16-ch space).
__global__ __launch_bounds__(512) void scatter_lin(
    const int* __restrict__ src, const int* __restrict__ dst,
    int* __restrict__ gcnt, int* __restrict__ staged,
    const float4* __restrict__ x4, const float* __restrict__ W,
    ushort_t* __restrict__ z, int E, int SBLK, int N, int NBKT)
{
    __shared__ float sW[512];
    __shared__ int lcnt[NBKT_MAX];
    __shared__ int lbase[NBKT_MAX];
    __shared__ int lcur[NBKT_MAX];
    int t = threadIdx.x, blk = blockIdx.x;
    if (blk < SBLK) {
        for (int b = t; b < NBKT; b += 512) { lcnt[b] = 0; lcur[b] = 0; }
        __syncthreads();
        int e0 = blk * EPB;
        int rd[16], rs[16];
        #pragma unroll
        for (int i = 0; i < 16; ++i) {
            int e = e0 + i * 512 + t;
            bool ok = (e < E);
            rd[i] = ok ? dst[e] : -1;
            rs[i] = ok ? src[e] : 0;
            if (ok) atomicAdd(&lcnt[rd[i] >> BKT_SHIFT], 1);
        }
        __syncthreads();
        for (int b = t; b < NBKT; b += 512)
            lbase[b] = atomicAdd(&gcnt[b], lcnt[b]);
        __syncthreads();
        #pragma unroll
        for (int i = 0; i < 16; ++i) {
            if (rd[i] >= 0) {
                int b = rd[i] >> BKT_SHIFT;
                int r = lbase[b] + atomicAdd(&lcur[b], 1);
                if (r < BCAP)   // statistically unreachable overflow guard
                    staged[(size_t)b * BCAP + r] =
                        ((rd[i] & (BKT_NODES - 1)) << 24) | rs[i];
            }
        }
    } else {
        sW[t] = W[t];                      // 32x16 = 512 floats
        __syncthreads();
        int n = (blk - SBLK) * 512 + t;
        if (n >= N) return;
        float a[16];
        #pragma unroll
        for (int c = 0; c < 16; ++c) a[c] = 0.f;
        const float4* xr = x4 + (size_t)n * 8;
        #pragma unroll
        for (int k4 = 0; k4 < 8; ++k4) {
            float4 xv = xr[k4];
            #pragma unroll
            for (int c = 0; c < 16; ++c) {
                a[c] += xv.x * sW[(k4 * 4 + 0) * 16 + c];
                a[c] += xv.y * sW[(k4 * 4 + 1) * 16 + c];
                a[c] += xv.z * sW[(k4 * 4 + 2) * 16 + c];
                a[c] += xv.w * sW[(k4 * 4 + 3) * 16 + c];
            }
        }
        uint_t w[8];
        #pragma unroll
        for (int i2 = 0; i2 < 8; ++i2)
            w[i2] = (uint_t)f2bf(a[2 * i2]) | ((uint_t)f2bf(a[2 * i2 + 1]) << 16);
        uint4* zo = (uint4*)(z + (size_t)n * 16);
        uint4 q0; q0.x = w[0]; q0.y = w[1]; q0.z = w[2]; q0.w = w[3];
        uint4 q1; q1.x = w[4]; q1.y = w[5]; q1.z = w[6]; q1.w = w[7];
        zo[0] = q0;     // cacheable: consumed by agg gathers next
        zo[1] = q1;
    }
}

// One 512-thread block per bucket: per-(node, src-quartile) LDS count ->
// 256-wide node scan (writes rp2 = {start,end} per node, absolute into the
// bucket-padded col layout) -> LDS place -> coalesced col flush. The
// quartile sub-sort keeps the agg gather sweep phase-local in src.
__global__ __launch_bounds__(512) void fine_fill(
    const int* __restrict__ staged, const int* __restrict__ gcnt,
    int2* __restrict__ rp2, int* __restrict__ col,
    int N, int NBKT, int q1, int q2, int q3)
{
    __shared__ int scnt[1024];   // [node][quartile]
    __shared__ int srel[1024];
    __shared__ int scur[1024];
    __shared__ int swsum[256];
    __shared__ int scol[BCAP];   // 32 KB
    int b = blockIdx.x, t = threadIdx.x;
    int n0 = b << BKT_SHIFT;
    int nn = min(BKT_NODES, N - n0);
    int e0 = b * BCAP;
    int m = min(gcnt[b], BCAP);

    for (int i = t; i < 1024; i += 512) { scnt[i] = 0; scur[i] = 0; }
    __syncthreads();
    for (int i = t; i < m; i += 512) {
        int v = staged[e0 + i];
        int dl = ((unsigned)v) >> 24;
        int s = v & 0xFFFFFF;
        int q = (s >= q2) ? ((s >= q3) ? 3 : 2) : ((s >= q1) ? 1 : 0);
        atomicAdd(&scnt[dl * 4 + q], 1);
    }
    __syncthreads();
    int c0 = 0, c1 = 0, c2 = 0, c3 = 0, tot = 0;
    if (t < 256) {
        c0 = scnt[t * 4 + 0]; c1 = scnt[t * 4 + 1];
        c2 = scnt[t * 4 + 2]; c3 = scnt[t * 4 + 3];
        tot = c0 + c1 + c2 + c3;
        swsum[t] = tot;
    }
    __syncthreads();
    for (int off = 1; off < 256; off <<= 1) {   // Hillis-Steele inclusive over nodes
        int add = (t < 256 && t >= off) ? swsum[t - off] : 0;
        __syncthreads();
        if (t < 256) swsum[t] += add;
        __syncthreads();
    }
    if (t < 256) {
        int excl = swsum[t] - tot;              // node-exclusive prefix
        srel[t * 4 + 0] = excl;
        srel[t * 4 + 1] = excl + c0;
        srel[t * 4 + 2] = excl + c0 + c1;
        srel[t * 4 + 3] = excl + c0 + c1 + c2;
        if (t < nn) rp2[n0 + t] = make_int2(e0 + excl, e0 + excl + tot);
    }
    __syncthreads();

    for (int i = t; i < m; i += 512) {
        int v = staged[e0 + i];
        int dl = ((unsigned)v) >> 24;
        int s = v & 0xFFFFFF;
        int q = (s >= q2) ? ((s >= q3) ? 3 : 2) : ((s >= q1) ? 1 : 0);
        int p = srel[dl * 4 + q] + atomicAdd(&scur[dl * 4 + q], 1);
        scol[p] = s;
    }
    __syncthreads();
    for (int i = t; i < m; i += 512) col[e0 + i] = scol[i];
}

// ---- Fused 16-ch aggregate + MLP ---------------------------------------
// Block = 256 threads = 64 nodes x 4 lanes; each lane handles 4 channels of
// the 16-ch z-row via uint2 (8B) loads. All 64 nodes lie in one bucket
// (64 | 256), so their col entries are one contiguous run -> LDS staged.
// s = z_i + sum z_j;  h = ReLU(s + ba);  o = h@Wb + bb  (16->32)
//   CHAIN:  z_next = ReLU(o)@Wc -> bf16 (feeds conv2's aggregation)
//   !CHAIN: o -> fp32 final output

template <bool CHAIN>
__global__ __launch_bounds__(256) void agg_mlp16(
    const ushort_t* __restrict__ zin, const int2* __restrict__ rp2,
    const int* __restrict__ col,
    const float* __restrict__ ba,
    const float* __restrict__ Wb, const float* __restrict__ bb,
    const float* __restrict__ Wc,
    void* __restrict__ outv, int N)
{
    __shared__ float sWb[16 * 32];
    __shared__ float sWc[32 * 16];
    __shared__ float sba[16], sbb[32];
    __shared__ float sh[NPB16 * 17];
    __shared__ float sr[NPB16 * 33];
    __shared__ int scol[SCOL_N16];

    int t = threadIdx.x;
    sWb[t] = Wb[t];  sWb[t + 256] = Wb[t + 256];
    if (CHAIN) { sWc[t] = Wc[t];  sWc[t + 256] = Wc[t + 256]; }
    if (t < 16) sba[t] = ba[t];
    if (t < 32) sbb[t] = bb[t];

    int base = blockIdx.x * NPB16;
    int last = min(base + NPB16, N) - 1;
    int kb = rp2[base].x;
    int kt = rp2[last].y;
    int tot = kt - kb;
    bool ovf = (tot > SCOL_N16);
    if (!ovf) {
        for (int i = t; i < tot; i += 256)
            scol[i] = __builtin_nontemporal_load(col + kb + i);
    }
    __syncthreads();

    int ln = t >> 2;          // node slot 0..63
    int sl = t & 3;           // channels 4*sl .. 4*sl+3
    int n  = base + ln;
    bool act = (n < N);
    const uint2* zp = (const uint2*)zin;   // row = 4 uint2 (16 bf16)

    if (act) {
        uint2 us = zp[(size_t)n * 4 + sl];
        float v0 = bflo(us.x), v1 = bfhi(us.x), v2 = bflo(us.y), v3 = bfhi(us.y);
        int2 r = rp2[n];
        int ks = r.x, ke = r.y;
        if (!ovf) {
            int k = ks - kb, kend = ke - kb;
            for (; k + 8 <= kend; k += 8) {
                int s0 = scol[k + 0], s1 = scol[k + 1], s2 = scol[k + 2], s3 = scol[k + 3];
                int s4 = scol[k + 4], s5 = scol[k + 5], s6 = scol[k + 6], s7 = scol[k + 7];
                uint2 u0 = zp[(size_t)s0 * 4 + sl];
                uint2 u1 = zp[(size_t)s1 * 4 + sl];
                uint2 u2 = zp[(size_t)s2 * 4 + sl];
                uint2 u3 = zp[(size_t)s3 * 4 + sl];
                uint2 u4 = zp[(size_t)s4 * 4 + sl];
                uint2 u5 = zp[(size_t)s5 * 4 + sl];
                uint2 u6 = zp[(size_t)s6 * 4 + sl];
                uint2 u7 = zp[(size_t)s7 * 4 + sl];
                v0 += ((bflo(u0.x) + bflo(u1.x)) + (bflo(u2.x) + bflo(u3.x)))
                    + ((bflo(u4.x) + bflo(u5.x)) + (bflo(u6.x) + bflo(u7.x)));
                v1 += ((bfhi(u0.x) + bfhi(u1.x)) + (bfhi(u2.x) + bfhi(u3.x)))
                    + ((bfhi(u4.x) + bfhi(u5.x)) + (bfhi(u6.x) + bfhi(u7.x)));
                v2 += ((bflo(u0.y) + bflo(u1.y)) + (bflo(u2.y) + bflo(u3.y)))
                    + ((bflo(u4.y) + bflo(u5.y)) + (bflo(u6.y) + bflo(u7.y)));
                v3 += ((bfhi(u0.y) + bfhi(u1.y)) + (bfhi(u2.y) + bfhi(u3.y)))
                    + ((bfhi(u4.y) + bfhi(u5.y)) + (bfhi(u6.y) + bfhi(u7.y)));
            }
            for (; k < kend; ++k) {
                uint2 u = zp[(size_t)scol[k] * 4 + sl];
                v0 += bflo(u.x); v1 += bfhi(u.x); v2 += bflo(u.y); v3 += bfhi(u.y);
            }
        } else {  // statistically unreachable
            for (int k = ks; k < ke; ++k) {
                uint2 u = zp[(size_t)col[k] * 4 + sl];
                v0 += bflo(u.x); v1 += bfhi(u.x); v2 += bflo(u.y); v3 += bfhi(u.y);
            }
        }
        int cb = sl * 4;
        sh[ln * 17 + cb + 0] = fmaxf(v0 + sba[cb + 0], 0.f);
        sh[ln * 17 + cb + 1] = fmaxf(v1 + sba[cb + 1], 0.f);
        sh[ln * 17 + cb + 2] = fmaxf(v2 + sba[cb + 2], 0.f);
        sh[ln * 17 + cb + 3] = fmaxf(v3 + sba[cb + 3], 0.f);
    }
    __syncthreads();

    if (act) {   // out channels 8*sl .. 8*sl+7 of o = h@Wb + bb
        int c0 = sl * 8;
        float o[8];
        #pragma unroll
        for (int j = 0; j < 8; ++j) o[j] = sbb[c0 + j];
        #pragma unroll
        for (int j = 0; j < 16; ++j) {
            float hj = sh[ln * 17 + j];
            #pragma unroll
            for (int cc = 0; cc < 8; ++cc)
                o[cc] += hj * sWb[j * 32 + c0 + cc];
        }
        if (CHAIN) {
            #pragma unroll
            for (int cc = 0; cc < 8; ++cc)
                sr[ln * 33 + c0 + cc] = fmaxf(o[cc], 0.f);
        } else {
            float* op = (float*)outv + (size_t)n * 32 + c0;
            #pragma unroll
            for (int cc = 0; cc < 8; ++cc)
                __builtin_nontemporal_store(o[cc], op + cc);
        }
    }
    if (CHAIN) {
        __syncthreads();
        if (act) {   // z_next channels 4*sl .. 4*sl+3 = ReLU(o) @ Wc
            int c0 = sl * 4;
            float a0 = 0.f, a1 = 0.f, a2 = 0.f, a3 = 0.f;
            #pragma unroll
            for (int j = 0; j < 32; ++j) {
                float rj = sr[ln * 33 + j];
                a0 += rj * sWc[j * 16 + c0 + 0];
                a1 += rj * sWc[j * 16 + c0 + 1];
                a2 += rj * sWc[j * 16 + c0 + 2];
                a3 += rj * sWc[j * 16 + c0 + 3];
            }
            uint_t p0 = (uint_t)f2bf(a0) | ((uint_t)f2bf(a1) << 16);
            uint_t p1 = (uint_t)f2bf(a2) | ((uint_t)f2bf(a3) << 16);
            uint_t* op = (uint_t*)outv + (size_t)n * 8 + sl * 2;
            op[0] = p0;    // cacheable: consumed by next conv's gather
            op[1] = p1;
        }
    }
}

// ---- Launch -------------------------------------------------------------

extern "C" void kernel_launch(void* const* d_in, const int* in_sizes, int n_in,
                              void* d_out, int out_size, void* d_ws, size_t ws_size,
                              hipStream_t stream) {
    const float* x  = (const float*)d_in[0];
    const int*   ei = (const int*)d_in[1];
    const float* W1 = (const float*)d_in[2];
    const float* b1 = (const float*)d_in[3];
    const float* W2 = (const float*)d_in[4];
    const float* b2 = (const float*)d_in[5];
    const float* W3 = (const float*)d_in[6];
    const float* b3 = (const float*)d_in[7];
    const float* W4 = (const float*)d_in[8];
    const float* b4 = (const float*)d_in[9];

    const int N = in_sizes[0] / 32;
    const int E = in_sizes[1] / 2;
    const int* src = ei;
    const int* dst = ei + E;

    const int NBKT = (N + BKT_NODES - 1) >> BKT_SHIFT;   // 391
    const int SBLK = (E + EPB - 1) / EPB;                // 306
    const int LINB = (N + 511) / 512;                    // 196

    char* ws = (char*)d_ws;
    size_t o = 0;
    auto alloc = [&](size_t bytes) -> char* {
        o = (o + 255) & ~(size_t)255;
        char* r = ws + o;
        o += bytes;
        return r;
    };
    int*      gcnt   = (int*)     alloc(4 * (size_t)NBKT);
    int*      staged = (int*)     alloc(4 * (size_t)NBKT * BCAP);   // 12.8 MB
    int*      col    = (int*)     alloc(4 * (size_t)NBKT * BCAP);   // 12.8 MB
    int2*     rp2    = (int2*)    alloc(8 * (size_t)N);
    ushort_t* zb     = (ushort_t*)alloc(2 * (size_t)N * 16);        // z1 = x@W1
    ushort_t* z2b    = (ushort_t*)alloc(2 * (size_t)N * 16);        // z2 = relu(out1)@W3

    hipMemsetAsync(gcnt, 0, 4 * (size_t)NBKT, stream);

    scatter_lin<<<SBLK + LINB, 512, 0, stream>>>(
        src, dst, gcnt, staged, (const float4*)x, W1, zb, E, SBLK, N, NBKT);

    int q1 = N / 4, q2 = N / 2, q3 = (3 * N) / 4;
    fine_fill<<<NBKT, 512, 0, stream>>>(staged, gcnt, rp2, col, N, NBKT, q1, q2, q3);

    agg_mlp16<true ><<<(N + NPB16 - 1) / NPB16, 256, 0, stream>>>(
        zb, rp2, col, b1, W2, b2, W3, z2b, N);
    agg_mlp16<false><<<(N + NPB16 - 1) / NPB16, 256, 0, stream>>>(
        z2b, rp2, col, b3, W4, b4, nullptr, d_out, N);
}

// Round 4
// 177.402 us; speedup vs baseline: 5.2715x; 1.0000x over previous
//
#include <hip/hip_runtime.h>

typedef unsigned short ushort_t;
typedef unsigned int uint_t;

#define BKT_SHIFT 6            // 64 dst-nodes per bucket
#define BKT_NODES 64
#define NBKT_MAX 1600          // >= ceil(100000/64)=1563
#define BCAP 2560              // slots/bucket; mean 1600, sigma~40 -> +24 sigma
#define EPB 8192               // edges per scatter block (512 thr x 16 in regs)

__device__ __forceinline__ ushort_t f2bf(float f) {
    unsigned u = __float_as_uint(f);
    unsigned r = (u + 0x7FFFu + ((u >> 16) & 1u)) >> 16;   // RNE
    return (ushort_t)r;
}
__device__ __forceinline__ float bflo(uint_t u) { return __uint_as_float(u << 16); }
__device__ __forceinline__ float bfhi(uint_t u) { return __uint_as_float(u & 0xFFFF0000u); }

// ---- fat kernel: range-claim bucket scatter  ||  z1 = x @ W1 (bf16) ----
// Scatter blocks: 16 edges/thread in REGISTERS; LDS histogram over 1563
// buckets; ONE global atomicAdd per (block,bucket) claims a contiguous range
// (~478K atomics, ~306 per address -> parallel across addresses); place via
// LDS rank atomics. Per-edge atomics never leave LDS (round-2 lesson).
// Lin blocks: per-node 32->16 matvec, bf16 out (GIN distributivity:
// (x_i + sum x_j)@W1 = z_i + sum z_j, so aggregation runs in 16-ch space;
// z table = 3.2 MB -> per-XCD-L2-resident, gather order irrelevant).
__global__ __launch_bounds__(512) void scatter_lin(
    const int* __restrict__ src, const int* __restrict__ dst,
    int* __restrict__ gcnt, int* __restrict__ staged,
    const float4* __restrict__ x4, const float* __restrict__ W,
    ushort_t* __restrict__ z, int E, int SBLK, int N, int NBKT)
{
    __shared__ float sW[512];
    __shared__ int lcnt[NBKT_MAX];
    __shared__ int lbase[NBKT_MAX];
    __shared__ int lcur[NBKT_MAX];
    int t = threadIdx.x, blk = blockIdx.x;
    if (blk < SBLK) {
        for (int b = t; b < NBKT; b += 512) { lcnt[b] = 0; lcur[b] = 0; }
        __syncthreads();
        int e0 = blk * EPB;
        int rd[16], rs[16];
        #pragma unroll
        for (int i = 0; i < 16; ++i) {
            int e = e0 + i * 512 + t;
            bool ok = (e < E);
            rd[i] = ok ? dst[e] : -1;
            rs[i] = ok ? src[e] : 0;
            if (ok) atomicAdd(&lcnt[rd[i] >> BKT_SHIFT], 1);
        }
        __syncthreads();
        for (int b = t; b < NBKT; b += 512)
            lbase[b] = atomicAdd(&gcnt[b], lcnt[b]);
        __syncthreads();
        #pragma unroll
        for (int i = 0; i < 16; ++i) {
            if (rd[i] >= 0) {
                int b = rd[i] >> BKT_SHIFT;
                int r = lbase[b] + atomicAdd(&lcur[b], 1);
                if (r < BCAP)   // statistically unreachable overflow guard
                    staged[(size_t)b * BCAP + r] =
                        ((rd[i] & (BKT_NODES - 1)) << 24) | rs[i];
            }
        }
    } else {
        sW[t] = W[t];                      // 32x16 = 512 floats
        __syncthreads();
        int n = (blk - SBLK) * 512 + t;
        if (n >= N) return;
        float a[16];
        #pragma unroll
        for (int c = 0; c < 16; ++c) a[c] = 0.f;
        const float4* xr = x4 + (size_t)n * 8;
        #pragma unroll
        for (int k4 = 0; k4 < 8; ++k4) {
            float4 xv = xr[k4];
            #pragma unroll
            for (int c = 0; c < 16; ++c) {
                a[c] += xv.x * sW[(k4 * 4 + 0) * 16 + c];
                a[c] += xv.y * sW[(k4 * 4 + 1) * 16 + c];
                a[c] += xv.z * sW[(k4 * 4 + 2) * 16 + c];
                a[c] += xv.w * sW[(k4 * 4 + 3) * 16 + c];
            }
        }
        uint_t w[8];
        #pragma unroll
        for (int i2 = 0; i2 < 8; ++i2)
            w[i2] = (uint_t)f2bf(a[2 * i2]) | ((uint_t)f2bf(a[2 * i2 + 1]) << 16);
        uint4* zo = (uint4*)(z + (size_t)n * 16);
        uint4 q0; q0.x = w[0]; q0.y = w[1]; q0.z = w[2]; q0.w = w[3];
        uint4 q1; q1.x = w[4]; q1.y = w[5]; q1.z = w[6]; q1.w = w[7];
        zo[0] = q0;     // cacheable: consumed by agg gathers next
        zo[1] = q1;
    }
}

// ---- Fused sort + aggregate + MLP --------------------------------------
// One 256-thread block per 64-node bucket (grid 1563, ~6/CU). Phase 1: read
// the bucket's contiguous staged run, node-sort it in LDS (count -> wave-0
// shuffle scan -> ranked place; q=s&3 subkey spreads the LDS atomics).
// Phase 2 (identical to verified round-3 agg): 64 node-quads, 4 lanes x 4ch,
// register accumulation over scol; s = z_i + sum z_j; h = ReLU(s + ba);
// o = h@Wb + bb  (16->32)
//   CHAIN:  z_next = ReLU(o)@Wc -> bf16 (feeds conv2's aggregation)
//   !CHAIN: o -> fp32 final output

template <bool CHAIN>
__global__ __launch_bounds__(256) void agg_sort_mlp(
    const ushort_t* __restrict__ zin, const int* __restrict__ staged,
    const int* __restrict__ gcnt,
    const float* __restrict__ ba,
    const float* __restrict__ Wb, const float* __restrict__ bb,
    const float* __restrict__ Wc,
    void* __restrict__ outv, int N)
{
    __shared__ float sWb[16 * 32];
    __shared__ float sWc[32 * 16];
    __shared__ float sba[16], sbb[32];
    __shared__ float sh[BKT_NODES * 17];
    __shared__ float sr[BKT_NODES * 33];
    __shared__ int scnt[256];       // [node][q]  (64 x 4)
    __shared__ int srel[256];
    __shared__ int scur[256];
    __shared__ int snode[BKT_NODES + 1];
    __shared__ int scol[BCAP];      // 10 KB

    int t = threadIdx.x;
    sWb[t] = Wb[t];  sWb[t + 256] = Wb[t + 256];
    if (CHAIN) { sWc[t] = Wc[t];  sWc[t + 256] = Wc[t + 256]; }
    if (t < 16) sba[t] = ba[t];
    if (t < 32) sbb[t] = bb[t];
    scnt[t] = 0;  scur[t] = 0;
    __syncthreads();

    int b = blockIdx.x;
    int m = min(gcnt[b], BCAP);
    const int* sp = staged + (size_t)b * BCAP;

    // count by (node, s&3)
    for (int i = t; i < m; i += 256) {
        int v = sp[i];
        atomicAdd(&scnt[(((unsigned)v >> 24) << 2) | (v & 3)], 1);
    }
    __syncthreads();

    // node-exclusive scan (wave 0, shuffle)
    if (t < 64) {
        int c0 = scnt[t * 4 + 0], c1 = scnt[t * 4 + 1];
        int c2 = scnt[t * 4 + 2], c3 = scnt[t * 4 + 3];
        int tot = c0 + c1 + c2 + c3;
        int sc = tot;
        #pragma unroll
        for (int off = 1; off < 64; off <<= 1) {
            int up = __shfl_up(sc, off, 64);
            if (t >= off) sc += up;
        }
        int excl = sc - tot;
        snode[t] = excl;
        if (t == 63) snode[64] = sc;
        srel[t * 4 + 0] = excl;
        srel[t * 4 + 1] = excl + c0;
        srel[t * 4 + 2] = excl + c0 + c1;
        srel[t * 4 + 3] = excl + c0 + c1 + c2;
    }
    __syncthreads();

    // ranked place into scol (staged run is L2-hot from the count pass)
    for (int i = t; i < m; i += 256) {
        int v = sp[i];
        int idx = (((unsigned)v >> 24) << 2) | (v & 3);
        int p = srel[idx] + atomicAdd(&scur[idx], 1);
        scol[p] = v & 0xFFFFFF;
    }
    __syncthreads();

    // gather + accumulate (verified round-3 inner loop)
    int ln = t >> 2;          // node slot 0..63
    int sl = t & 3;           // channels 4*sl .. 4*sl+3
    int n  = (b << BKT_SHIFT) + ln;
    bool act = (n < N);
    const uint2* zp = (const uint2*)zin;   // row = 4 uint2 (16 bf16)

    if (act) {
        uint2 us = zp[(size_t)n * 4 + sl];
        float v0 = bflo(us.x), v1 = bfhi(us.x), v2 = bflo(us.y), v3 = bfhi(us.y);
        int k = snode[ln], kend = snode[ln + 1];
        for (; k + 8 <= kend; k += 8) {
            int s0 = scol[k + 0], s1 = scol[k + 1], s2 = scol[k + 2], s3 = scol[k + 3];
            int s4 = scol[k + 4], s5 = scol[k + 5], s6 = scol[k + 6], s7 = scol[k + 7];
            uint2 u0 = zp[(size_t)s0 * 4 + sl];
            uint2 u1 = zp[(size_t)s1 * 4 + sl];
            uint2 u2 = zp[(size_t)s2 * 4 + sl];
            uint2 u3 = zp[(size_t)s3 * 4 + sl];
            uint2 u4 = zp[(size_t)s4 * 4 + sl];
            uint2 u5 = zp[(size_t)s5 * 4 + sl];
            uint2 u6 = zp[(size_t)s6 * 4 + sl];
            uint2 u7 = zp[(size_t)s7 * 4 + sl];
            v0 += ((bflo(u0.x) + bflo(u1.x)) + (bflo(u2.x) + bflo(u3.x)))
                + ((bflo(u4.x) + bflo(u5.x)) + (bflo(u6.x) + bflo(u7.x)));
            v1 += ((bfhi(u0.x) + bfhi(u1.x)) + (bfhi(u2.x) + bfhi(u3.x)))
                + ((bfhi(u4.x) + bfhi(u5.x)) + (bfhi(u6.x) + bfhi(u7.x)));
            v2 += ((bflo(u0.y) + bflo(u1.y)) + (bflo(u2.y) + bflo(u3.y)))
                + ((bflo(u4.y) + bflo(u5.y)) + (bflo(u6.y) + bflo(u7.y)));
            v3 += ((bfhi(u0.y) + bfhi(u1.y)) + (bfhi(u2.y) + bfhi(u3.y)))
                + ((bfhi(u4.y) + bfhi(u5.y)) + (bfhi(u6.y) + bfhi(u7.y)));
        }
        for (; k < kend; ++k) {
            uint2 u = zp[(size_t)scol[k] * 4 + sl];
            v0 += bflo(u.x); v1 += bfhi(u.x); v2 += bflo(u.y); v3 += bfhi(u.y);
        }
        int cb = sl * 4;
        sh[ln * 17 + cb + 0] = fmaxf(v0 + sba[cb + 0], 0.f);
        sh[ln * 17 + cb + 1] = fmaxf(v1 + sba[cb + 1], 0.f);
        sh[ln * 17 + cb + 2] = fmaxf(v2 + sba[cb + 2], 0.f);
        sh[ln * 17 + cb + 3] = fmaxf(v3 + sba[cb + 3], 0.f);
    }
    __syncthreads();

    if (act) {   // out channels 8*sl .. 8*sl+7 of o = h@Wb + bb
        int c0 = sl * 8;
        float o[8];
        #pragma unroll
        for (int j = 0; j < 8; ++j) o[j] = sbb[c0 + j];
        #pragma unroll
        for (int j = 0; j < 16; ++j) {
            float hj = sh[ln * 17 + j];
            #pragma unroll
            for (int cc = 0; cc < 8; ++cc)
                o[cc] += hj * sWb[j * 32 + c0 + cc];
        }
        if (CHAIN) {
            #pragma unroll
            for (int cc = 0; cc < 8; ++cc)
                sr[ln * 33 + c0 + cc] = fmaxf(o[cc], 0.f);
        } else {
            float* op = (float*)outv + (size_t)n * 32 + c0;
            #pragma unroll
            for (int cc = 0; cc < 8; ++cc)
                __builtin_nontemporal_store(o[cc], op + cc);
        }
    }
    if (CHAIN) {
        __syncthreads();
        if (act) {   // z_next channels 4*sl .. 4*sl+3 = ReLU(o) @ Wc
            int c0 = sl * 4;
            float a0 = 0.f, a1 = 0.f, a2 = 0.f, a3 = 0.f;
            #pragma unroll
            for (int j = 0; j < 32; ++j) {
                float rj = sr[ln * 33 + j];
                a0 += rj * sWc[j * 16 + c0 + 0];
                a1 += rj * sWc[j * 16 + c0 + 1];
                a2 += rj * sWc[j * 16 + c0 + 2];
                a3 += rj * sWc[j * 16 + c0 + 3];
            }
            uint_t p0 = (uint_t)f2bf(a0) | ((uint_t)f2bf(a1) << 16);
            uint_t p1 = (uint_t)f2bf(a2) | ((uint_t)f2bf(a3) << 16);
            uint_t* op = (uint_t*)outv + (size_t)n * 8 + sl * 2;
            op[0] = p0;    // cacheable: consumed by next conv's gather
            op[1] = p1;
        }
    }
}

// ---- Launch -------------------------------------------------------------

extern "C" void kernel_launch(void* const* d_in, const int* in_sizes, int n_in,
                              void* d_out, int out_size, void* d_ws, size_t ws_size,
                              hipStream_t stream) {
    const float* x  = (const float*)d_in[0];
    const int*   ei = (const int*)d_in[1];
    const float* W1 = (const float*)d_in[2];
    const float* b1 = (const float*)d_in[3];
    const float* W2 = (const float*)d_in[4];
    const float* b2 = (const float*)d_in[5];
    const float* W3 = (const float*)d_in[6];
    const float* b3 = (const float*)d_in[7];
    const float* W4 = (const float*)d_in[8];
    const float* b4 = (const float*)d_in[9];

    const int N = in_sizes[0] / 32;
    const int E = in_sizes[1] / 2;
    const int* src = ei;
    const int* dst = ei + E;

    const int NBKT = (N + BKT_NODES - 1) >> BKT_SHIFT;   // 1563
    const int SBLK = (E + EPB - 1) / EPB;                // 306
    const int LINB = (N + 511) / 512;                    // 196

    char* ws = (char*)d_ws;
    size_t o = 0;
    auto alloc = [&](size_t bytes) -> char* {
        o = (o + 255) & ~(size_t)255;
        char* r = ws + o;
        o += bytes;
        return r;
    };
    int*      gcnt   = (int*)     alloc(4 * (size_t)NBKT);
    int*      staged = (int*)     alloc(4 * (size_t)NBKT * BCAP);   // 16 MB
    ushort_t* zb     = (ushort_t*)alloc(2 * (size_t)N * 16);        // z1 = x@W1
    ushort_t* z2b    = (ushort_t*)alloc(2 * (size_t)N * 16);        // z2 = relu(out1)@W3

    hipMemsetAsync(gcnt, 0, 4 * (size_t)NBKT, stream);

    scatter_lin<<<SBLK + LINB, 512, 0, stream>>>(
        src, dst, gcnt, staged, (const float4*)x, W1, zb, E, SBLK, N, NBKT);

    agg_sort_mlp<true ><<<NBKT, 256, 0, stream>>>(
        zb, staged, gcnt, b1, W2, b2, W3, z2b, N);
    agg_sort_mlp<false><<<NBKT, 256, 0, stream>>>(
        z2b, staged, gcnt, b3, W4, b4, nullptr, d_out, N);
}